// Round 1
// baseline (159.501 us; speedup 1.0000x reference)
//
#include <hip/hip_runtime.h>

using u16    = unsigned short;
using f32x4  = __attribute__((ext_vector_type(4))) float;
using bf16x8 = __attribute__((ext_vector_type(8))) __bf16;
using u16x4  = __attribute__((ext_vector_type(4))) u16;
using i32x4  = __attribute__((ext_vector_type(4))) int;

// Problem constants: B=2, S=2048, D=1024, H=16, DK=64, M = B*S = 4096.

__device__ __forceinline__ u16 f2bf(float f) {      // RNE f32 -> bf16
  unsigned u = __float_as_uint(f);
  u += 0x7fffu + ((u >> 16) & 1u);
  return (u16)(u >> 16);
}

typedef __attribute__((address_space(1))) const void GVoid;
typedef __attribute__((address_space(3))) void LVoid;

__device__ __forceinline__ void gload_lds16(const void* g, void* l) {
  // async global->LDS, 16B per lane; LDS dest is wave-uniform-base + lane*16
  __builtin_amdgcn_global_load_lds((GVoid*)g, (LVoid*)l, 16, 0, 0);
}

// ---------------- fp32 -> bf16 conversion kernels ----------------
__global__ void cvt_qkv(const float* __restrict__ a, const float* __restrict__ b,
                        const float* __restrict__ c,
                        u16* __restrict__ oa, u16* __restrict__ ob, u16* __restrict__ oc) {
  int y = blockIdx.y;
  const float* s = (y == 0) ? a : (y == 1) ? b : c;
  u16* d = (y == 0) ? oa : (y == 1) ? ob : oc;
  int i = blockIdx.x * 256 + threadIdx.x;
  f32x4 v = ((const f32x4*)s)[i];
  u16x4 r;
#pragma unroll
  for (int j = 0; j < 4; ++j) r[j] = f2bf(v[j]);
  ((u16x4*)d)[i] = r;
}

__global__ void cvt_w(const float* __restrict__ a, const float* __restrict__ b,
                      const float* __restrict__ c, const float* __restrict__ dd,
                      u16* __restrict__ oa, u16* __restrict__ ob,
                      u16* __restrict__ oc, u16* __restrict__ od) {
  int y = blockIdx.y;
  const float* s = (y == 0) ? a : (y == 1) ? b : (y == 2) ? c : dd;
  u16* d = (y == 0) ? oa : (y == 1) ? ob : (y == 2) ? oc : od;
  int i = blockIdx.x * 256 + threadIdx.x;
  f32x4 v = ((const f32x4*)s)[i];
  u16x4 r;
#pragma unroll
  for (int j = 0; j < 4; ++j) r[j] = f2bf(v[j]);
  ((u16x4*)d)[i] = r;
}

// ---------------- GEMM: out[m,n] = sum_k X[m,k] * W[n,k]  (x @ W.T) ----------------
// 128x128 tile, BK=64, 4 waves (2x2), 16x16x32 bf16 MFMA.
// epi: -1 -> derive from blockIdx.z (0/1 -> head layout [B,H,S,DK], 2 -> V-transposed [B,H,DK,S])
//       2 -> fp32 row-major [M,N] (final projection into d_out)
__global__ __launch_bounds__(256, 2) void gemm_bt(const u16* __restrict__ X,
                                                  const u16* __restrict__ W,
                                                  void* __restrict__ out, int epi) {
  __shared__ alignas(16) char lds[32768];  // A tile [128][64]bf16, B tile at +16384
  const int t = threadIdx.x;
  const int lane = t & 63, wid = t >> 6;
  const int g = lane >> 4, r16 = lane & 15;
  const int wm = wid >> 1, wn = wid & 1;
  const int m0 = blockIdx.x * 128, n0 = blockIdx.y * 128;

  const u16* Xp = X;
  const u16* Wp = W;
  void* op = out;
  int e = epi;
  if (epi < 0) {
    int z = blockIdx.z;
    Xp += (size_t)z * 4194304;   // Xq/Xk/Xv consecutive
    Wp += (size_t)z * 1048576;   // Wq/Wk/Wv consecutive
    op = (void*)((u16*)out + (size_t)z * 4194304);  // Qh/Kh/Vt consecutive
    e = (z == 2) ? 1 : 0;
  }
  const char* Ab = (const char*)Xp;
  const char* Bb = (const char*)Wp;

  f32x4 acc[4][4] = {};

  for (int kk = 0; kk < 1024; kk += 64) {
    // stage A[128][64] + B[128][64]; linear LDS dest, inverse-swizzled global src
#pragma unroll
    for (int i = 0; i < 4; ++i) {
      int ci = i * 256 + t;
      int row = ci >> 3;
      int cbs = ((ci & 7) << 4) ^ ((row & 7) << 4);
      gload_lds16(Ab + (size_t)(m0 + row) * 2048 + kk * 2 + cbs, lds + ci * 16);
      gload_lds16(Bb + (size_t)(n0 + row) * 2048 + kk * 2 + cbs, lds + 16384 + ci * 16);
    }
    __syncthreads();
#pragma unroll
    for (int kc = 0; kc < 2; ++kc) {
      bf16x8 af[4], bfr[4];
#pragma unroll
      for (int mf = 0; mf < 4; ++mf) {
        int row = wm * 64 + mf * 16 + r16;
        af[mf] = *(const bf16x8*)(lds + row * 128 + ((64 * kc + 16 * g) ^ ((row & 7) << 4)));
      }
#pragma unroll
      for (int nf = 0; nf < 4; ++nf) {
        int row = wn * 64 + nf * 16 + r16;
        bfr[nf] = *(const bf16x8*)(lds + 16384 + row * 128 + ((64 * kc + 16 * g) ^ ((row & 7) << 4)));
      }
#pragma unroll
      for (int mf = 0; mf < 4; ++mf)
#pragma unroll
        for (int nf = 0; nf < 4; ++nf)
          acc[mf][nf] = __builtin_amdgcn_mfma_f32_16x16x32_bf16(af[mf], bfr[nf], acc[mf][nf], 0, 0, 0);
    }
    __syncthreads();
  }

  // epilogue — C/D layout: col = lane&15 (n), row = 4*(lane>>4)+reg (m)
#pragma unroll
  for (int mf = 0; mf < 4; ++mf) {
#pragma unroll
    for (int nf = 0; nf < 4; ++nf) {
      int mb = m0 + wm * 64 + mf * 16 + 4 * g;
      int n = n0 + wn * 64 + nf * 16 + r16;
      if (e == 2) {
        float* O = (float*)op;
#pragma unroll
        for (int r = 0; r < 4; ++r) O[(size_t)(mb + r) * 1024 + n] = acc[mf][nf][r];
      } else if (e == 0) {  // [B,H,S,DK]
        u16* O = (u16*)op;
        int bb = mb >> 11, h = n >> 6, dk = n & 63;
#pragma unroll
        for (int r = 0; r < 4; ++r) {
          int s = (mb + r) & 2047;
          O[((size_t)(bb * 16 + h) * 2048 + s) * 64 + dk] = f2bf(acc[mf][nf][r]);
        }
      } else {  // [B,H,DK,S]  (V transposed; 4 regs = 4 consecutive s -> 8B store)
        u16* O = (u16*)op;
        int bb = mb >> 11, s = mb & 2047, h = n >> 6, dk = n & 63;
        u16x4 pv;
#pragma unroll
        for (int r = 0; r < 4; ++r) pv[r] = f2bf(acc[mf][nf][r]);
        *(u16x4*)(O + ((size_t)(bb * 16 + h) * 64 + dk) * 2048 + s) = pv;
      }
    }
  }
}

// ---------------- flash attention, one (b,h,q-tile of 64) per block ----------------
// 4 waves, each owns 16 q rows. Swapped QK^T: mfma(A=K, B=Q) -> lane holds
// S[k = kf*16+4g+r][q = lane&15]; softmax row-reduce = in-reg + shfl_xor(16,32).
__global__ __launch_bounds__(256, 2) void attn_kern(const u16* __restrict__ Qh,
                                                    const u16* __restrict__ Kh,
                                                    const u16* __restrict__ Vt,
                                                    const int* __restrict__ mask,
                                                    u16* __restrict__ ctx) {
  __shared__ alignas(16) char lds[24576];  // K[64][64] | Vt[64][64] @8192 | P @16384 (4 waves x 2KB)
  const int t = threadIdx.x;
  const int wid = t >> 6, lane = t & 63;
  const int g = lane >> 4, r16 = lane & 15;
  const int qt = blockIdx.x, bh = blockIdx.y;
  const int b = bh >> 4, h = bh & 15;
  const char* qbytes = (const char*)Qh;
  const char* kbytes = (const char*)Kh;
  const char* vbytes = (const char*)Vt;

  // Q fragments (B operand): lane = q-col r16, dk = kc*32 + 8g..+8
  const size_t qrow = (size_t)bh * 2048 + qt * 64 + wid * 16 + r16;
  bf16x8 qf0 = *(const bf16x8*)(qbytes + qrow * 128 + 16 * g);
  bf16x8 qf1 = *(const bf16x8*)(qbytes + qrow * 128 + 64 + 16 * g);

  float m_run = -__builtin_inff(), l_run = 0.f;
  f32x4 o[4] = {};  // o[df][r] = O[q=4g+r][d=df*16+r16]

  const int qg = qt * 64 + wid * 16 + r16;
  const int* mrow_base = mask + ((size_t)b * 2048 + qg) * 2048;

  for (int kt = 0; kt < 32; ++kt) {
    // stage K tile (rows=k, cols=dk) and Vt tile (rows=d, cols=k), XOR-swizzled src
#pragma unroll
    for (int i = 0; i < 2; ++i) {
      int ci = i * 256 + t;
      int row = ci >> 3;
      int cbs = ((ci & 7) << 4) ^ ((row & 7) << 4);
      gload_lds16(kbytes + ((size_t)bh * 2048 + kt * 64 + row) * 128 + cbs, lds + ci * 16);
      gload_lds16(vbytes + ((size_t)bh * 64 + row) * 4096 + kt * 128 + cbs, lds + 8192 + ci * 16);
    }
    __syncthreads();

    // QK^T
    f32x4 sf[4];
#pragma unroll
    for (int kf = 0; kf < 4; ++kf) {
      int row = kf * 16 + r16;
      int sw = (row & 7) << 4;
      bf16x8 ka0 = *(const bf16x8*)(lds + row * 128 + ((16 * g) ^ sw));
      bf16x8 ka1 = *(const bf16x8*)(lds + row * 128 + ((64 + 16 * g) ^ sw));
      f32x4 z = {};
      z = __builtin_amdgcn_mfma_f32_16x16x32_bf16(ka0, qf0, z, 0, 0, 0);
      sf[kf] = __builtin_amdgcn_mfma_f32_16x16x32_bf16(ka1, qf1, z, 0, 0, 0);
    }

    // scale + mask (exactly like reference: masked -> -1e9), tile max
    const int* mrow = mrow_base + kt * 64;
    float tmax = -__builtin_inff();
#pragma unroll
    for (int kf = 0; kf < 4; ++kf) {
      i32x4 mv = *(const i32x4*)(mrow + kf * 16 + 4 * g);
#pragma unroll
      for (int r = 0; r < 4; ++r) {
        float sv = sf[kf][r] * 0.125f;
        sv = (mv[r] == 0) ? -1e9f : sv;
        sf[kf][r] = sv;
        tmax = fmaxf(tmax, sv);
      }
    }
    tmax = fmaxf(tmax, __shfl_xor(tmax, 16, 64));
    tmax = fmaxf(tmax, __shfl_xor(tmax, 32, 64));
    float m_new = fmaxf(m_run, tmax);
    float alpha = __expf(m_run - m_new);  // first tile: exp(-inf)=0
    float ps = 0.f;
#pragma unroll
    for (int kf = 0; kf < 4; ++kf)
#pragma unroll
      for (int r = 0; r < 4; ++r) {
        float p = __expf(sf[kf][r] - m_new);
        sf[kf][r] = p;
        ps += p;
      }
    ps += __shfl_xor(ps, 16, 64);
    ps += __shfl_xor(ps, 32, 64);
    l_run = l_run * alpha + ps;
    m_run = m_new;

    // rescale O (per-q alpha lives at lane q; O rows are q=4g+r)
    float ar0 = __shfl(alpha, 4 * g + 0, 64);
    float ar1 = __shfl(alpha, 4 * g + 1, 64);
    float ar2 = __shfl(alpha, 4 * g + 2, 64);
    float ar3 = __shfl(alpha, 4 * g + 3, 64);
#pragma unroll
    for (int df = 0; df < 4; ++df) {
      o[df][0] *= ar0; o[df][1] *= ar1; o[df][2] *= ar2; o[df][3] *= ar3;
    }

    // P -> per-wave swizzled LDS strip (regs 0..3 are 4 consecutive k -> b64 write)
    char* pbase = lds + 16384 + wid * 2048;
    int psw = (r16 & 7) << 4;
#pragma unroll
    for (int kf = 0; kf < 4; ++kf) {
      u16x4 pv;
#pragma unroll
      for (int r = 0; r < 4; ++r) pv[r] = f2bf(sf[kf][r]);
      *(u16x4*)(pbase + r16 * 128 + ((kf * 32 + 8 * g) ^ psw)) = pv;
    }

    // PV: O[q][d] += sum_k P[q,k] * Vt[d,k]
#pragma unroll
    for (int kc = 0; kc < 2; ++kc) {
      bf16x8 pa = *(const bf16x8*)(pbase + r16 * 128 + ((64 * kc + 16 * g) ^ psw));
#pragma unroll
      for (int df = 0; df < 4; ++df) {
        int vrow = df * 16 + r16;
        bf16x8 vb = *(const bf16x8*)(lds + 8192 + vrow * 128 +
                                     ((64 * kc + 16 * g) ^ ((vrow & 7) << 4)));
        o[df] = __builtin_amdgcn_mfma_f32_16x16x32_bf16(pa, vb, o[df], 0, 0, 0);
      }
    }
    __syncthreads();
  }

  // normalize by 1/l
  float rl = 1.f / l_run;
  float lr0 = __shfl(rl, 4 * g + 0, 64);
  float lr1 = __shfl(rl, 4 * g + 1, 64);
  float lr2 = __shfl(rl, 4 * g + 2, 64);
  float lr3 = __shfl(rl, 4 * g + 3, 64);
#pragma unroll
  for (int df = 0; df < 4; ++df) {
    o[df][0] *= lr0; o[df][1] *= lr1; o[df][2] *= lr2; o[df][3] *= lr3;
  }

  // transpose via LDS (per-wave 4KB, K/V regions are dead now) and store ctx [B,S,D] bf16
  float* obase = (float*)(lds + wid * 4096);
#pragma unroll
  for (int df = 0; df < 4; ++df)
#pragma unroll
    for (int r = 0; r < 4; ++r)
      obase[(4 * g + r) * 64 + df * 16 + r16] = o[df][r];

  const size_t orow0 = (size_t)b * 2048 + qt * 64 + wid * 16;
#pragma unroll
  for (int i = 0; i < 16; ++i) {
    float val = obase[i * 64 + lane];
    ctx[(orow0 + i) * 1024 + h * 64 + lane] = f2bf(val);
  }
}

// ---------------- launch ----------------
extern "C" void kernel_launch(void* const* d_in, const int* in_sizes, int n_in,
                              void* d_out, int out_size, void* d_ws, size_t ws_size,
                              hipStream_t stream) {
  const float* q  = (const float*)d_in[0];
  const float* k  = (const float*)d_in[1];
  const float* v  = (const float*)d_in[2];
  const int* mask = (const int*)d_in[3];
  const float* Wq = (const float*)d_in[4];
  const float* Wk = (const float*)d_in[5];
  const float* Wv = (const float*)d_in[6];
  const float* Wo = (const float*)d_in[7];

  u16* ws = (u16*)d_ws;
  const size_t NX = (size_t)4096 * 1024;  // 4,194,304 elems
  const size_t NW = (size_t)1024 * 1024;
  u16* Xq  = ws;                    // Xq, Xk, Xv consecutive (3*NX)
  u16* Wqb = ws + 3 * NX;           // Wq, Wk, Wv, Wo bf16 consecutive (4*NW)
  u16* Qh  = Wqb + 4 * NW;          // Qh, Kh, Vt consecutive (3*NX)
  u16* ctx = Qh + 3 * NX;           // bf16 [B*S, D]   -> total 64 MB ws

  cvt_qkv<<<dim3(4096, 3), 256, 0, stream>>>(q, k, v, Xq, Xq + NX, Xq + 2 * NX);
  cvt_w<<<dim3(1024, 4), 256, 0, stream>>>(Wq, Wk, Wv, Wo,
                                           Wqb, Wqb + NW, Wqb + 2 * NW, Wqb + 3 * NW);
  gemm_bt<<<dim3(32, 8, 3), 256, 0, stream>>>(Xq, Wqb, Qh, -1);
  attn_kern<<<dim3(32, 32), 256, 0, stream>>>(Qh, Qh + NX, Qh + 2 * NX, mask, ctx);
  gemm_bt<<<dim3(32, 8, 1), 256, 0, stream>>>(ctx, Wqb + 3 * NW, d_out, 2);
}

// Round 2
// 158.001 us; speedup vs baseline: 1.0095x; 1.0095x over previous
//
#include <hip/hip_runtime.h>

using u16    = unsigned short;
using f32x4  = __attribute__((ext_vector_type(4))) float;
using bf16x8 = __attribute__((ext_vector_type(8))) __bf16;
using u16x4  = __attribute__((ext_vector_type(4))) u16;
using i32x4  = __attribute__((ext_vector_type(4))) int;

// Problem constants: B=2, S=2048, D=1024, H=16, DK=64, M = B*S = 4096.
// Softmax runs in exp2 domain: Q is pre-scaled by 0.125*log2(e) at projection.

__device__ __forceinline__ u16 f2bf(float f) {  // single v_cvt (RNE) on gfx950
  union { __bf16 b; u16 u; } c; c.b = (__bf16)f; return c.u;
}

typedef __attribute__((address_space(1))) const void GVoid;
typedef __attribute__((address_space(3))) void LVoid;

__device__ __forceinline__ void gload_lds16(const void* g, void* l) {
  __builtin_amdgcn_global_load_lds((GVoid*)g, (LVoid*)l, 16, 0, 0);
}

// ---------------- fp32 -> bf16 conversion kernels ----------------
__global__ void cvt_qkv(const float* __restrict__ a, const float* __restrict__ b,
                        const float* __restrict__ c,
                        u16* __restrict__ oa, u16* __restrict__ ob, u16* __restrict__ oc) {
  int y = blockIdx.y;
  const float* s = (y == 0) ? a : (y == 1) ? b : c;
  u16* d = (y == 0) ? oa : (y == 1) ? ob : oc;
  int i = blockIdx.x * 256 + threadIdx.x;
  f32x4 v = ((const f32x4*)s)[i];
  u16x4 r;
#pragma unroll
  for (int j = 0; j < 4; ++j) r[j] = f2bf(v[j]);
  ((u16x4*)d)[i] = r;
}

__global__ void cvt_w(const float* __restrict__ a, const float* __restrict__ b,
                      const float* __restrict__ c, const float* __restrict__ dd,
                      u16* __restrict__ oa, u16* __restrict__ ob,
                      u16* __restrict__ oc, u16* __restrict__ od) {
  int y = blockIdx.y;
  const float* s = (y == 0) ? a : (y == 1) ? b : (y == 2) ? c : dd;
  u16* d = (y == 0) ? oa : (y == 1) ? ob : (y == 2) ? oc : od;
  int i = blockIdx.x * 256 + threadIdx.x;
  f32x4 v = ((const f32x4*)s)[i];
  u16x4 r;
#pragma unroll
  for (int j = 0; j < 4; ++j) r[j] = f2bf(v[j]);
  ((u16x4*)d)[i] = r;
}

// ---------------- GEMM: out[m,n] = sum_k X[m,k] * W[n,k]  (x @ W.T) ----------------
__global__ __launch_bounds__(256, 2) void gemm_bt(const u16* __restrict__ X,
                                                  const u16* __restrict__ W,
                                                  void* __restrict__ out, int epi) {
  __shared__ alignas(16) char lds[32768];
  const int t = threadIdx.x;
  const int lane = t & 63, wid = t >> 6;
  const int g = lane >> 4, r16 = lane & 15;
  const int wm = wid >> 1, wn = wid & 1;
  const int m0 = blockIdx.x * 128, n0 = blockIdx.y * 128;

  const u16* Xp = X;
  const u16* Wp = W;
  void* op = out;
  int e = epi;
  float qsc = 1.0f;
  if (epi < 0) {
    int z = blockIdx.z;
    Xp += (size_t)z * 4194304;
    Wp += (size_t)z * 1048576;
    op = (void*)((u16*)out + (size_t)z * 4194304);
    e = (z == 2) ? 1 : 0;
    if (z == 0) qsc = 0.18033688011f;  // 0.125 * log2(e) folded into Q
  }
  const char* Ab = (const char*)Xp;
  const char* Bb = (const char*)Wp;

  f32x4 acc[4][4] = {};

  for (int kk = 0; kk < 1024; kk += 64) {
#pragma unroll
    for (int i = 0; i < 4; ++i) {
      int ci = i * 256 + t;
      int row = ci >> 3;
      int cbs = ((ci & 7) << 4) ^ ((row & 7) << 4);
      gload_lds16(Ab + (size_t)(m0 + row) * 2048 + kk * 2 + cbs, lds + ci * 16);
      gload_lds16(Bb + (size_t)(n0 + row) * 2048 + kk * 2 + cbs, lds + 16384 + ci * 16);
    }
    __syncthreads();
#pragma unroll
    for (int kc = 0; kc < 2; ++kc) {
      bf16x8 af[4], bfr[4];
#pragma unroll
      for (int mf = 0; mf < 4; ++mf) {
        int row = wm * 64 + mf * 16 + r16;
        af[mf] = *(const bf16x8*)(lds + row * 128 + ((64 * kc + 16 * g) ^ ((row & 7) << 4)));
      }
#pragma unroll
      for (int nf = 0; nf < 4; ++nf) {
        int row = wn * 64 + nf * 16 + r16;
        bfr[nf] = *(const bf16x8*)(lds + 16384 + row * 128 + ((64 * kc + 16 * g) ^ ((row & 7) << 4)));
      }
#pragma unroll
      for (int mf = 0; mf < 4; ++mf)
#pragma unroll
        for (int nf = 0; nf < 4; ++nf)
          acc[mf][nf] = __builtin_amdgcn_mfma_f32_16x16x32_bf16(af[mf], bfr[nf], acc[mf][nf], 0, 0, 0);
    }
    __syncthreads();
  }

#pragma unroll
  for (int mf = 0; mf < 4; ++mf) {
#pragma unroll
    for (int nf = 0; nf < 4; ++nf) {
      int mb = m0 + wm * 64 + mf * 16 + 4 * g;
      int n = n0 + wn * 64 + nf * 16 + r16;
      if (e == 2) {
        float* O = (float*)op;
#pragma unroll
        for (int r = 0; r < 4; ++r) O[(size_t)(mb + r) * 1024 + n] = acc[mf][nf][r];
      } else if (e == 0) {  // [B,H,S,DK]
        u16* O = (u16*)op;
        int bb = mb >> 11, h = n >> 6, dk = n & 63;
#pragma unroll
        for (int r = 0; r < 4; ++r) {
          int s = (mb + r) & 2047;
          O[((size_t)(bb * 16 + h) * 2048 + s) * 64 + dk] = f2bf(acc[mf][nf][r] * qsc);
        }
      } else {  // [B,H,DK,S]
        u16* O = (u16*)op;
        int bb = mb >> 11, s = mb & 2047, h = n >> 6, dk = n & 63;
        u16x4 pv;
#pragma unroll
        for (int r = 0; r < 4; ++r) pv[r] = f2bf(acc[mf][nf][r]);
        *(u16x4*)(O + ((size_t)(bb * 16 + h) * 64 + dk) * 2048 + s) = pv;
      }
    }
  }
}

// ---------------- flash attention ----------------
// 4 waves x 16 q rows; double-buffered K/V staging (counted vmcnt, raw barriers);
// mask folded into MFMA C-init; exp2-domain softmax; defer-max rescale.
__global__ __launch_bounds__(256, 4) void attn_kern(const u16* __restrict__ Qh,
                                                    const u16* __restrict__ Kh,
                                                    const u16* __restrict__ Vt,
                                                    const int* __restrict__ mask,
                                                    u16* __restrict__ ctx) {
  __shared__ alignas(16) char lds[40960];  // buf0 K|V 16K, buf1 K|V 16K, P 8K @32768
  const int t = threadIdx.x;
  const int wid = t >> 6, lane = t & 63;
  const int g = lane >> 4, r16 = lane & 15;
  const int qt = blockIdx.x, bh = blockIdx.y;
  const int b = bh >> 4, h = bh & 15;
  const char* qbytes = (const char*)Qh;
  const char* kbytes = (const char*)Kh;
  const char* vbytes = (const char*)Vt;

  const size_t qrow = (size_t)bh * 2048 + qt * 64 + wid * 16 + r16;
  bf16x8 qf0 = *(const bf16x8*)(qbytes + qrow * 128 + 16 * g);
  bf16x8 qf1 = *(const bf16x8*)(qbytes + qrow * 128 + 64 + 16 * g);

  float m_run = -__builtin_inff(), l_run = 0.f;
  f32x4 o[4] = {};
  const int qg = qt * 64 + wid * 16 + r16;
  const int* mrow_base = mask + ((size_t)b * 2048 + qg) * 2048;

#define STAGE(BUF, KT2)                                                        \
  {                                                                            \
    _Pragma("unroll") for (int i = 0; i < 2; ++i) {                            \
      int ci = i * 256 + t;                                                    \
      int row = ci >> 3;                                                       \
      int cbs = ((ci & 7) << 4) ^ ((row & 7) << 4);                            \
      gload_lds16(kbytes + ((size_t)bh * 2048 + (KT2) * 64 + row) * 128 + cbs, \
                  lds + (BUF)*16384 + ci * 16);                                \
      gload_lds16(vbytes + ((size_t)bh * 64 + row) * 4096 + (KT2)*128 + cbs,   \
                  lds + (BUF)*16384 + 8192 + ci * 16);                         \
    }                                                                          \
  }

  STAGE(0, 0);  // prologue: 4 vmem in flight

  for (int kt = 0; kt < 32; ++kt) {
    const int cur = kt & 1;
    const char* cbuf = lds + cur * 16384;

    // mask loads FIRST (so compiler's wait for them is vmcnt(4), not 0)
    const int* mrow = mrow_base + kt * 64;
    i32x4 mv0 = *(const i32x4*)(mrow + 0 * 16 + 4 * g);
    i32x4 mv1 = *(const i32x4*)(mrow + 1 * 16 + 4 * g);
    i32x4 mv2 = *(const i32x4*)(mrow + 2 * 16 + 4 * g);
    i32x4 mv3 = *(const i32x4*)(mrow + 3 * 16 + 4 * g);
    __builtin_amdgcn_sched_barrier(0);  // keep mask loads older than stage loads

    if (kt < 31) {
      STAGE(cur ^ 1, kt + 1);
      asm volatile("s_waitcnt vmcnt(8)" ::: "memory");  // cur's 4 stage loads done
    } else {
      asm volatile("s_waitcnt vmcnt(4)" ::: "memory");
    }
    __builtin_amdgcn_s_barrier();
    asm volatile("" ::: "memory");
    __builtin_amdgcn_sched_barrier(0);

    // QK^T, mask bias as MFMA C-init.  S2[k][q] (log2-domain, Q pre-scaled)
    auto qkf = [&](int kf, i32x4 mv) -> f32x4 {
      int row = kf * 16 + r16;
      int sw = (row & 7) << 4;
      bf16x8 ka0 = *(const bf16x8*)(cbuf + row * 128 + ((16 * g) ^ sw));
      bf16x8 ka1 = *(const bf16x8*)(cbuf + row * 128 + ((64 + 16 * g) ^ sw));
      f32x4 z;
#pragma unroll
      for (int r = 0; r < 4; ++r) z[r] = (mv[r] == 0) ? -1e9f : 0.f;
      z = __builtin_amdgcn_mfma_f32_16x16x32_bf16(ka0, qf0, z, 0, 0, 0);
      return __builtin_amdgcn_mfma_f32_16x16x32_bf16(ka1, qf1, z, 0, 0, 0);
    };
    f32x4 sf[4];
    sf[0] = qkf(0, mv0); sf[1] = qkf(1, mv1); sf[2] = qkf(2, mv2); sf[3] = qkf(3, mv3);

    float tmax = -__builtin_inff();
#pragma unroll
    for (int kf = 0; kf < 4; ++kf)
#pragma unroll
      for (int r = 0; r < 4; ++r) tmax = fmaxf(tmax, sf[kf][r]);
    tmax = fmaxf(tmax, __shfl_xor(tmax, 16, 64));
    tmax = fmaxf(tmax, __shfl_xor(tmax, 32, 64));

    if (!__all(tmax <= m_run + 8.f)) {  // defer-max: skip rescale when max stable
      float m_new = fmaxf(m_run, tmax);
      float alpha = __builtin_amdgcn_exp2f(m_run - m_new);
      float ar0 = __shfl(alpha, 4 * g + 0, 64);
      float ar1 = __shfl(alpha, 4 * g + 1, 64);
      float ar2 = __shfl(alpha, 4 * g + 2, 64);
      float ar3 = __shfl(alpha, 4 * g + 3, 64);
#pragma unroll
      for (int df = 0; df < 4; ++df) {
        o[df][0] *= ar0; o[df][1] *= ar1; o[df][2] *= ar2; o[df][3] *= ar3;
      }
      l_run *= alpha;
      m_run = m_new;
    }

    float ps = 0.f;
#pragma unroll
    for (int kf = 0; kf < 4; ++kf)
#pragma unroll
      for (int r = 0; r < 4; ++r) {
        float p = __builtin_amdgcn_exp2f(sf[kf][r] - m_run);
        sf[kf][r] = p;
        ps += p;
      }
    ps += __shfl_xor(ps, 16, 64);
    ps += __shfl_xor(ps, 32, 64);
    l_run += ps;

    // P -> per-wave swizzled LDS strip, then PV
    char* pbase = lds + 32768 + wid * 2048;
    int psw = (r16 & 7) << 4;
#pragma unroll
    for (int kf = 0; kf < 4; ++kf) {
      u16x4 pv;
#pragma unroll
      for (int r = 0; r < 4; ++r) pv[r] = f2bf(sf[kf][r]);
      *(u16x4*)(pbase + r16 * 128 + ((kf * 32 + 8 * g) ^ psw)) = pv;
    }

#pragma unroll
    for (int kc = 0; kc < 2; ++kc) {
      bf16x8 pa = *(const bf16x8*)(pbase + r16 * 128 + ((64 * kc + 16 * g) ^ psw));
#pragma unroll
      for (int df = 0; df < 4; ++df) {
        int vrow = df * 16 + r16;
        bf16x8 vb = *(const bf16x8*)(cbuf + 8192 + vrow * 128 +
                                     ((64 * kc + 16 * g) ^ ((vrow & 7) << 4)));
        o[df] = __builtin_amdgcn_mfma_f32_16x16x32_bf16(pa, vb, o[df], 0, 0, 0);
      }
    }

    asm volatile("" ::: "memory");
    __builtin_amdgcn_s_barrier();  // all reads of cur done before next stage
    asm volatile("" ::: "memory");
  }
#undef STAGE

  float rl = 1.f / l_run;
  float lr0 = __shfl(rl, 4 * g + 0, 64);
  float lr1 = __shfl(rl, 4 * g + 1, 64);
  float lr2 = __shfl(rl, 4 * g + 2, 64);
  float lr3 = __shfl(rl, 4 * g + 3, 64);
#pragma unroll
  for (int df = 0; df < 4; ++df) {
    o[df][0] *= lr0; o[df][1] *= lr1; o[df][2] *= lr2; o[df][3] *= lr3;
  }

  // transpose via per-wave LDS strip, store ctx [B,S,D] bf16
  float* obase = (float*)(lds + wid * 4096);
#pragma unroll
  for (int df = 0; df < 4; ++df)
#pragma unroll
    for (int r = 0; r < 4; ++r)
      obase[(4 * g + r) * 64 + df * 16 + r16] = o[df][r];

  const size_t orow0 = (size_t)b * 2048 + qt * 64 + wid * 16;
#pragma unroll
  for (int i = 0; i < 16; ++i) {
    float val = obase[i * 64 + lane];
    ctx[(orow0 + i) * 1024 + h * 64 + lane] = f2bf(val);
  }
}

// ---------------- launch ----------------
extern "C" void kernel_launch(void* const* d_in, const int* in_sizes, int n_in,
                              void* d_out, int out_size, void* d_ws, size_t ws_size,
                              hipStream_t stream) {
  const float* q  = (const float*)d_in[0];
  const float* k  = (const float*)d_in[1];
  const float* v  = (const float*)d_in[2];
  const int* mask = (const int*)d_in[3];
  const float* Wq = (const float*)d_in[4];
  const float* Wk = (const float*)d_in[5];
  const float* Wv = (const float*)d_in[6];
  const float* Wo = (const float*)d_in[7];

  u16* ws = (u16*)d_ws;
  const size_t NX = (size_t)4096 * 1024;
  const size_t NW = (size_t)1024 * 1024;
  u16* Xq  = ws;
  u16* Wqb = ws + 3 * NX;
  u16* Qh  = Wqb + 4 * NW;
  u16* ctx = Qh + 3 * NX;

  cvt_qkv<<<dim3(4096, 3), 256, 0, stream>>>(q, k, v, Xq, Xq + NX, Xq + 2 * NX);
  cvt_w<<<dim3(1024, 4), 256, 0, stream>>>(Wq, Wk, Wv, Wo,
                                           Wqb, Wqb + NW, Wqb + 2 * NW, Wqb + 3 * NW);
  gemm_bt<<<dim3(32, 8, 3), 256, 0, stream>>>(Xq, Wqb, Qh, -1);
  attn_kern<<<dim3(32, 32), 256, 0, stream>>>(Qh, Qh + NX, Qh + 2 * NX, mask, ctx);
  gemm_bt<<<dim3(32, 8, 1), 256, 0, stream>>>(ctx, Wqb + 3 * NW, d_out, 2);
}

// Round 3
// 141.217 us; speedup vs baseline: 1.1295x; 1.1188x over previous
//
#include <hip/hip_runtime.h>

using u16    = unsigned short;
using u32    = unsigned int;
using f32x4  = __attribute__((ext_vector_type(4))) float;
using f32x16 = __attribute__((ext_vector_type(16))) float;
using bf16x8 = __attribute__((ext_vector_type(8))) __bf16;
using u16x4  = __attribute__((ext_vector_type(4))) u16;
using u32x2  = __attribute__((ext_vector_type(2))) u32;
using u32x4  = __attribute__((ext_vector_type(4))) u32;
using i32x4  = __attribute__((ext_vector_type(4))) int;

// B=2, S=2048, D=1024, H=16, DK=64, M=B*S=4096.
// Softmax in exp2 domain: Q pre-scaled by 0.125*log2(e) in projection epilogue.

__device__ __forceinline__ u16 f2bf(float f) {
  union { __bf16 b; u16 u; } c; c.b = (__bf16)f; return c.u;
}

typedef __attribute__((address_space(1))) const void GVoid;
typedef __attribute__((address_space(3))) void LVoid;

__device__ __forceinline__ void gload_lds16(const void* g, void* l) {
  __builtin_amdgcn_global_load_lds((GVoid*)g, (LVoid*)l, 16, 0, 0);
}

// ---------------- fp32 -> bf16 conversion ----------------
__global__ void cvt_qkv(const float* __restrict__ a, const float* __restrict__ b,
                        const float* __restrict__ c,
                        u16* __restrict__ oa, u16* __restrict__ ob, u16* __restrict__ oc) {
  int y = blockIdx.y;
  const float* s = (y == 0) ? a : (y == 1) ? b : c;
  u16* d = (y == 0) ? oa : (y == 1) ? ob : oc;
  int i = blockIdx.x * 256 + threadIdx.x;
  f32x4 v = ((const f32x4*)s)[i];
  u16x4 r;
#pragma unroll
  for (int j = 0; j < 4; ++j) r[j] = f2bf(v[j]);
  ((u16x4*)d)[i] = r;
}

__global__ void cvt_w(const float* __restrict__ a, const float* __restrict__ b,
                      const float* __restrict__ c, const float* __restrict__ dd,
                      u16* __restrict__ oa, u16* __restrict__ ob,
                      u16* __restrict__ oc, u16* __restrict__ od) {
  int y = blockIdx.y;
  const float* s = (y == 0) ? a : (y == 1) ? b : (y == 2) ? c : dd;
  u16* d = (y == 0) ? oa : (y == 1) ? ob : (y == 2) ? oc : od;
  int i = blockIdx.x * 256 + threadIdx.x;
  f32x4 v = ((const f32x4*)s)[i];
  u16x4 r;
#pragma unroll
  for (int j = 0; j < 4; ++j) r[j] = f2bf(v[j]);
  ((u16x4*)d)[i] = r;
}

// ---------------- mask bit-pack: [B,S,S] int32 -> [B,S,S/32] u32 ----------------
__global__ void pack_mask(const int* __restrict__ m, u32* __restrict__ mp) {
  int idx = blockIdx.x * 256 + threadIdx.x;  // 2*2048*64 = 262144 words
  const i32x4* src = (const i32x4*)(m + (size_t)idx * 32);
  u32 w = 0;
#pragma unroll
  for (int j = 0; j < 8; ++j) {
    i32x4 v = src[j];
#pragma unroll
    for (int e = 0; e < 4; ++e) w |= (v[e] != 0 ? 1u : 0u) << (j * 4 + e);
  }
  mp[idx] = w;
}

// ---------------- GEMM: out[m,n] = sum_k X[m,k]*W[n,k] (x @ W.T) ----------------
__global__ __launch_bounds__(256, 2) void gemm_bt(const u16* __restrict__ X,
                                                  const u16* __restrict__ W,
                                                  void* __restrict__ out, int epi) {
  __shared__ alignas(16) char lds[32768];
  const int t = threadIdx.x;
  const int lane = t & 63, wid = t >> 6;
  const int g = lane >> 4, r16 = lane & 15;
  const int wm = wid >> 1, wn = wid & 1;
  const int m0 = blockIdx.x * 128, n0 = blockIdx.y * 128;

  const u16* Xp = X;
  const u16* Wp = W;
  void* op = out;
  int e = epi;
  float qsc = 1.0f;
  if (epi < 0) {
    int z = blockIdx.z;
    Xp += (size_t)z * 4194304;
    Wp += (size_t)z * 1048576;
    op = (void*)((u16*)out + (size_t)z * 4194304);
    e = (z == 2) ? 1 : 0;
    if (z == 0) qsc = 0.18033688011f;  // 0.125 * log2(e) folded into Q
  }
  const char* Ab = (const char*)Xp;
  const char* Bb = (const char*)Wp;

  f32x4 acc[4][4] = {};

  for (int kk = 0; kk < 1024; kk += 64) {
#pragma unroll
    for (int i = 0; i < 4; ++i) {
      int ci = i * 256 + t;
      int row = ci >> 3;
      int cbs = ((ci & 7) << 4) ^ ((row & 7) << 4);
      gload_lds16(Ab + (size_t)(m0 + row) * 2048 + kk * 2 + cbs, lds + ci * 16);
      gload_lds16(Bb + (size_t)(n0 + row) * 2048 + kk * 2 + cbs, lds + 16384 + ci * 16);
    }
    __syncthreads();
#pragma unroll
    for (int kc = 0; kc < 2; ++kc) {
      bf16x8 af[4], bfr[4];
#pragma unroll
      for (int mf = 0; mf < 4; ++mf) {
        int row = wm * 64 + mf * 16 + r16;
        af[mf] = *(const bf16x8*)(lds + row * 128 + ((64 * kc + 16 * g) ^ ((row & 7) << 4)));
      }
#pragma unroll
      for (int nf = 0; nf < 4; ++nf) {
        int row = wn * 64 + nf * 16 + r16;
        bfr[nf] = *(const bf16x8*)(lds + 16384 + row * 128 + ((64 * kc + 16 * g) ^ ((row & 7) << 4)));
      }
#pragma unroll
      for (int mf = 0; mf < 4; ++mf)
#pragma unroll
        for (int nf = 0; nf < 4; ++nf)
          acc[mf][nf] = __builtin_amdgcn_mfma_f32_16x16x32_bf16(af[mf], bfr[nf], acc[mf][nf], 0, 0, 0);
    }
    __syncthreads();
  }

#pragma unroll
  for (int mf = 0; mf < 4; ++mf) {
#pragma unroll
    for (int nf = 0; nf < 4; ++nf) {
      int mb = m0 + wm * 64 + mf * 16 + 4 * g;
      int n = n0 + wn * 64 + nf * 16 + r16;
      if (e == 2) {
        float* O = (float*)op;
#pragma unroll
        for (int r = 0; r < 4; ++r) O[(size_t)(mb + r) * 1024 + n] = acc[mf][nf][r];
      } else if (e == 0) {  // [B,H,S,DK]
        u16* O = (u16*)op;
        int bb = mb >> 11, h = n >> 6, dk = n & 63;
#pragma unroll
        for (int r = 0; r < 4; ++r) {
          int s = (mb + r) & 2047;
          O[((size_t)(bb * 16 + h) * 2048 + s) * 64 + dk] = f2bf(acc[mf][nf][r] * qsc);
        }
      } else {  // [B,H,DK,S]
        u16* O = (u16*)op;
        int bb = mb >> 11, s = mb & 2047, h = n >> 6, dk = n & 63;
        u16x4 pv;
#pragma unroll
        for (int r = 0; r < 4; ++r) pv[r] = f2bf(acc[mf][nf][r]);
        *(u16x4*)(O + ((size_t)(bb * 16 + h) * 64 + dk) * 2048 + s) = pv;
      }
    }
  }
}

// ---------------- flash attention, 32x32 swapped, in-register softmax ----------------
// 4 waves x 32 q rows (QBLK=128); KVBLK=64 double-buffered; lane-local P row;
// T12 cvt_pk+permlane32_swap P->A-fragment; bit-packed mask prefetched 1 tile ahead.
__global__ __launch_bounds__(256, 2) void attn_kern(const u16* __restrict__ Qh,
                                                    const u16* __restrict__ Kh,
                                                    const u16* __restrict__ Vt,
                                                    const u32* __restrict__ mp,
                                                    u16* __restrict__ ctx) {
  __shared__ alignas(16) char lds[32768];  // dbuf x (K[64][64] | V[64][64])
  const int t = threadIdx.x;
  const int wid = t >> 6, lane = t & 63;
  const int hi = lane >> 5, l31 = lane & 31;

  // XCD-aware swizzle of 512 blocks (16 q-tiles x 32 bh): 64-block chunks per XCD
  const int wg = (blockIdx.x & 7) * 64 + (blockIdx.x >> 3);
  const int qt = wg & 15, bh = wg >> 4;
  const int b = bh >> 4, h = bh & 15;

  const char* qbytes = (const char*)Qh;
  const char* kbytes = (const char*)Kh;
  const char* vbytes = (const char*)Vt;

  const int qbase = qt * 128 + wid * 32;
  const int qg = qbase + l31;

  // Q fragments (B operand of mfma32): lane: q-col = l31, dk = 16c + 8*hi + j
  bf16x8 qf[4];
#pragma unroll
  for (int c = 0; c < 4; ++c)
    qf[c] = *(const bf16x8*)(qbytes + ((size_t)bh * 2048 + qg) * 128 + 32 * c + 16 * hi);

  // packed mask row: 64 u32 words per q-row
  const u32* mrow = mp + ((size_t)b * 2048 + qg) * 64;

  float m_run = -__builtin_inff(), l_run = 0.f;
  f32x16 o[2] = {};  // o[db][r] = O[q=crow(r,hi)][d=db*32+l31] (unnormalized)

#define STAGE(BUF, KT2)                                                        \
  {                                                                            \
    _Pragma("unroll") for (int i = 0; i < 2; ++i) {                            \
      int ci = i * 256 + t;                                                    \
      int row = ci >> 3;                                                       \
      int cbs = ((ci & 7) << 4) ^ ((row & 7) << 4);                            \
      gload_lds16(kbytes + ((size_t)bh * 2048 + (KT2) * 64 + row) * 128 + cbs, \
                  lds + (BUF)*16384 + ci * 16);                                \
      gload_lds16(vbytes + ((size_t)bh * 64 + row) * 4096 + (KT2)*128 + cbs,   \
                  lds + (BUF)*16384 + 8192 + ci * 16);                         \
    }                                                                          \
  }

  STAGE(0, 0);
  __builtin_amdgcn_sched_barrier(0);
  u32x2 mcur = *(const u32x2*)(mrow);  // words for tile 0
  __builtin_amdgcn_sched_barrier(0);

  for (int kt = 0; kt < 32; ++kt) {
    const int cur = kt & 1;
    const char* cb = lds + cur * 16384;
    u32x2 mnext;

    if (kt < 31) {
      STAGE(cur ^ 1, kt + 1);
      __builtin_amdgcn_sched_barrier(0);
      mnext = *(const u32x2*)(mrow + (kt + 1) * 2);
      __builtin_amdgcn_sched_barrier(0);
      asm volatile("s_waitcnt vmcnt(5)" ::: "memory");  // drain cur's 4 stage + mcur
    } else {
      mnext = mcur;
      asm volatile("s_waitcnt vmcnt(1)" ::: "memory");
    }
    __builtin_amdgcn_s_barrier();
    asm volatile("" ::: "memory");
    __builtin_amdgcn_sched_barrier(0);

    // ---- QK^T: S[k][q], C-init from mask bits (bit k-within-32 = (r&3)+8*(r>>2)+4*hi)
    u32 wa = mcur.x >> (4 * hi);
    u32 wb = mcur.y >> (4 * hi);
    f32x16 s0, s1;
#pragma unroll
    for (int r = 0; r < 16; ++r) {
      int bit = (r & 3) + 8 * (r >> 2);
      s0[r] = ((wa >> bit) & 1u) ? 0.f : -1e9f;
      s1[r] = ((wb >> bit) & 1u) ? 0.f : -1e9f;
    }
#pragma unroll
    for (int c = 0; c < 4; ++c) {
      int row0 = l31, row1 = 32 + l31;
      int col = (32 * c + 16 * hi);
      bf16x8 k0 = *(const bf16x8*)(cb + row0 * 128 + (col ^ ((row0 & 7) << 4)));
      bf16x8 k1 = *(const bf16x8*)(cb + row1 * 128 + (col ^ ((row1 & 7) << 4)));
      s0 = __builtin_amdgcn_mfma_f32_32x32x16_bf16(k0, qf[c], s0, 0, 0, 0);
      s1 = __builtin_amdgcn_mfma_f32_32x32x16_bf16(k1, qf[c], s1, 0, 0, 0);
    }

    // ---- softmax (lane-local row halves; partner = lane^32)
    float tm = -__builtin_inff();
#pragma unroll
    for (int r = 0; r < 16; ++r) tm = fmaxf(tm, fmaxf(s0[r], s1[r]));
    tm = fmaxf(tm, __shfl_xor(tm, 32, 64));

    if (!__all(tm <= m_run + 6.f)) {  // defer-max
      float m_new = fmaxf(m_run, tm);
      float alpha = __builtin_amdgcn_exp2f(m_run - m_new);
#pragma unroll
      for (int r = 0; r < 16; ++r) {
        float av = __shfl(alpha, (r & 3) + 8 * (r >> 2) + 4 * hi, 64);
        o[0][r] *= av;
        o[1][r] *= av;
      }
      l_run *= alpha;
      m_run = m_new;
    }

    float ps = 0.f;
#pragma unroll
    for (int r = 0; r < 16; ++r) {
      float p0 = __builtin_amdgcn_exp2f(s0[r] - m_run);
      float p1 = __builtin_amdgcn_exp2f(s1[r] - m_run);
      s0[r] = p0; s1[r] = p1;
      ps += p0 + p1;
    }
    ps += __shfl_xor(ps, 32, 64);
    l_run += ps;

    // ---- P -> bf16 A-fragments (16 cvt_pk + 8 permlane32_swap), k lane-local
    u32 w[16];
#pragma unroll
    for (int kb = 0; kb < 2; ++kb) {
#pragma unroll
      for (int ss = 0; ss < 2; ++ss) {
        const f32x16& sp = kb ? s1 : s0;
        u32 A0, B0, A1, B1;
        asm("v_cvt_pk_bf16_f32 %0, %1, %2" : "=v"(A0) : "v"(sp[8*ss+0]), "v"(sp[8*ss+1]));
        asm("v_cvt_pk_bf16_f32 %0, %1, %2" : "=v"(B0) : "v"(sp[8*ss+2]), "v"(sp[8*ss+3]));
        asm("v_cvt_pk_bf16_f32 %0, %1, %2" : "=v"(A1) : "v"(sp[8*ss+4]), "v"(sp[8*ss+5]));
        asm("v_cvt_pk_bf16_f32 %0, %1, %2" : "=v"(B1) : "v"(sp[8*ss+6]), "v"(sp[8*ss+7]));
        asm("v_permlane32_swap_b32 %0, %1" : "+v"(A0), "+v"(A1));
        asm("v_permlane32_swap_b32 %0, %1" : "+v"(B0), "+v"(B1));
        int f = 2 * kb + ss;
        w[4*f+0] = A0; w[4*f+1] = B0; w[4*f+2] = A1; w[4*f+3] = B1;
      }
    }

    // ---- PV: O[q][d] += P[q,k] * V[k,d]   (V from Vt[d][k] tile in LDS)
#pragma unroll
    for (int db = 0; db < 2; ++db) {
      int vrow = db * 32 + l31;
      int vsw = (vrow & 7) << 4;
#pragma unroll
      for (int ks = 0; ks < 4; ++ks) {
        bf16x8 pa = __builtin_bit_cast(bf16x8, u32x4{w[4*ks], w[4*ks+1], w[4*ks+2], w[4*ks+3]});
        bf16x8 vb = *(const bf16x8*)(cb + 8192 + vrow * 128 + ((32 * ks + 16 * hi) ^ vsw));
        o[db] = __builtin_amdgcn_mfma_f32_32x32x16_bf16(pa, vb, o[db], 0, 0, 0);
      }
    }

    mcur = mnext;
    asm volatile("" ::: "memory");
    __builtin_amdgcn_s_barrier();  // all reads of cur done before it is restaged
    asm volatile("" ::: "memory");
  }
#undef STAGE

  // ---- epilogue: normalize, store ctx [B,S,D] bf16
  float rl = 1.f / l_run;
#pragma unroll
  for (int r = 0; r < 16; ++r) {
    float rv = __shfl(rl, (r & 3) + 8 * (r >> 2) + 4 * hi, 64);
    int q = qbase + (r & 3) + 8 * (r >> 2) + 4 * hi;
    size_t rowp = ((size_t)b * 2048 + q) * 1024 + h * 64 + l31;
    ctx[rowp]      = f2bf(o[0][r] * rv);
    ctx[rowp + 32] = f2bf(o[1][r] * rv);
  }
}

// ---------------- launch ----------------
extern "C" void kernel_launch(void* const* d_in, const int* in_sizes, int n_in,
                              void* d_out, int out_size, void* d_ws, size_t ws_size,
                              hipStream_t stream) {
  const float* q  = (const float*)d_in[0];
  const float* k  = (const float*)d_in[1];
  const float* v  = (const float*)d_in[2];
  const int* mask = (const int*)d_in[3];
  const float* Wq = (const float*)d_in[4];
  const float* Wk = (const float*)d_in[5];
  const float* Wv = (const float*)d_in[6];
  const float* Wo = (const float*)d_in[7];

  u16* ws = (u16*)d_ws;
  const size_t NX = (size_t)4096 * 1024;
  const size_t NW = (size_t)1024 * 1024;
  u16* Xq  = ws;                    // dead after QKV GEMM -> reused for packed mask
  u16* Wqb = ws + 3 * NX;
  u16* Qh  = Wqb + 4 * NW;
  u16* ctx = Qh + 3 * NX;
  u32* mpk = (u32*)Xq;              // 1 MB, written after QKV GEMM

  cvt_qkv<<<dim3(4096, 3), 256, 0, stream>>>(q, k, v, Xq, Xq + NX, Xq + 2 * NX);
  cvt_w<<<dim3(1024, 4), 256, 0, stream>>>(Wq, Wk, Wv, Wo,
                                           Wqb, Wqb + NW, Wqb + 2 * NW, Wqb + 3 * NW);
  gemm_bt<<<dim3(32, 8, 3), 256, 0, stream>>>(Xq, Wqb, Qh, -1);
  pack_mask<<<dim3(1024), 256, 0, stream>>>(mask, mpk);
  attn_kern<<<dim3(512), 256, 0, stream>>>(Qh, Qh + NX, Qh + 2 * NX, mpk, ctx);
  gemm_bt<<<dim3(32, 8, 1), 256, 0, stream>>>(ctx, Wqb + 3 * NW, d_out, 2);
}